// Round 2
// baseline (330.569 us; speedup 1.0000x reference)
//
#include <hip/hip_runtime.h>
#include <math.h>

// SE4 squeeze-excite, B=8, C=64, H=W=256, 4x4 patch grid (64x64 patches), SQ=256.
// ALL I/O is float32 (per reference setup_inputs dtypes). fp32 compute.
//
// Kernels:
//   1. pool:    per-patch mean  -> ws.pooled [8][1024] fp32   (cat order (i*4+j)*C + c)
//   2. reduce:  s = mish(pooled @ reduce_w^T + reduce_b)  [8][256] fp32
//   3. expand:  g = sigmoid(s @ expand_w^T + expand_b)    [8][1024] fp32
//   4. scale:   out = t * g[b, (i*4+j)*C + c]  (float4 per thread)

#define Bsz 8
#define Csz 64
#define Hsz 256
#define Wsz 256
#define SQsz 256
#define C16 1024   // 16*C

// ---------------- kernel 1: patch pooling ----------------
// grid = B*C*16 = 8192 blocks of 256 threads. p = bid & 15 (= i*4+j), bc = bid>>4.
// Patch: 64 rows x 64 cols fp32 = 1024 float4 groups; each thread sums 4 groups.
__global__ __launch_bounds__(256) void pool_kernel(const float* __restrict__ t,
                                                   float* __restrict__ pooled) {
    int bid = blockIdx.x;
    int p   = bid & 15;
    int bc  = bid >> 4;          // b*C + c
    int i   = p >> 2, j = p & 3;
    const float* base = t + (((size_t)bc * Hsz + (size_t)i * 64) * Wsz + (size_t)j * 64);
    int tid = threadIdx.x;
    float sum = 0.f;
#pragma unroll
    for (int k = 0; k < 4; ++k) {
        int g    = tid + k * 256;          // 0..1023
        int row  = g >> 4;
        int col4 = g & 15;
        float4 v = *(const float4*)(base + (size_t)row * Wsz + col4 * 4);
        sum += v.x + v.y + v.z + v.w;
    }
    // wave reduction (64 lanes)
#pragma unroll
    for (int off = 32; off > 0; off >>= 1) sum += __shfl_down(sum, off, 64);
    __shared__ float wsum[4];
    if ((tid & 63) == 0) wsum[tid >> 6] = sum;
    __syncthreads();
    if (tid == 0) {
        float s = wsum[0] + wsum[1] + wsum[2] + wsum[3];
        int b = bc >> 6;          // /C
        int c = bc & 63;
        pooled[b * C16 + p * Csz + c] = s * (1.0f / 4096.0f);
    }
}

// ---------------- kernel 2: s = mish(pooled @ reduce_w^T + reduce_b) ----------------
// grid = 8 blocks (one per b), 256 threads (one per sq output). dot length 1024.
__global__ __launch_bounds__(256) void reduce_kernel(const float* __restrict__ pooled,
                                                     const float* __restrict__ reduce_w,
                                                     const float* __restrict__ reduce_b,
                                                     float* __restrict__ s_out) {
    int b = blockIdx.x, tid = threadIdx.x;
    __shared__ float pl[C16];
    for (int k = tid; k < C16; k += 256) pl[k] = pooled[b * C16 + k];
    __syncthreads();
    const float* wrow = reduce_w + (size_t)tid * C16;
    float acc = 0.f;
#pragma unroll 4
    for (int k = 0; k < C16; k += 4) {
        float4 v = *(const float4*)(wrow + k);
        acc = fmaf(v.x, pl[k + 0], acc);
        acc = fmaf(v.y, pl[k + 1], acc);
        acc = fmaf(v.z, pl[k + 2], acc);
        acc = fmaf(v.w, pl[k + 3], acc);
    }
    acc += reduce_b[tid];
    // mish(x) = x * tanh(softplus(x))
    float sp = (acc > 15.f) ? acc : log1pf(expf(acc));
    s_out[b * SQsz + tid] = acc * tanhf(sp);
}

// ---------------- kernel 3: g = sigmoid(s @ expand_w^T + expand_b) ----------------
// grid = 8 blocks, 256 threads; each thread computes 4 outputs. dot length 256.
__global__ __launch_bounds__(256) void expand_kernel(const float* __restrict__ s_in,
                                                     const float* __restrict__ expand_w,
                                                     const float* __restrict__ expand_b,
                                                     float* __restrict__ g_out) {
    int b = blockIdx.x, tid = threadIdx.x;
    __shared__ float sv[SQsz];
    sv[tid] = s_in[b * SQsz + tid];
    __syncthreads();
#pragma unroll
    for (int kk = 0; kk < 4; ++kk) {
        int o = tid + kk * 256;
        const float* wrow = expand_w + (size_t)o * SQsz;
        float acc = 0.f;
#pragma unroll 4
        for (int q = 0; q < SQsz; q += 4) {
            float4 v = *(const float4*)(wrow + q);
            acc = fmaf(v.x, sv[q + 0], acc);
            acc = fmaf(v.y, sv[q + 1], acc);
            acc = fmaf(v.z, sv[q + 2], acc);
            acc = fmaf(v.w, sv[q + 3], acc);
        }
        acc += expand_b[o];
        g_out[b * C16 + o] = 1.0f / (1.0f + expf(-acc));
    }
}

// ---------------- kernel 4: out = t * gate ----------------
// One thread per float4 (never crosses a patch-column boundary: 4 | 64).
// total groups = 33,554,432/4 = 8,388,608 -> 32768 blocks x 256 threads.
__global__ __launch_bounds__(256) void scale_kernel(const float* __restrict__ t,
                                                    const float* __restrict__ g,
                                                    float* __restrict__ out) {
    unsigned int idx = blockIdx.x * 256u + threadIdx.x;   // float4 group index
    int w4 = idx & 63;                // w/4
    int h  = (idx >> 6) & 255;
    int c  = (idx >> 14) & 63;
    int b  = idx >> 20;
    int p  = ((h >> 6) << 2) | (w4 >> 4);    // i*4 + j
    float gate = g[(b << 10) + (p << 6) + c];
    float4 v = *(const float4*)(t + (size_t)idx * 4);
    float4 r;
    r.x = v.x * gate;
    r.y = v.y * gate;
    r.z = v.z * gate;
    r.w = v.w * gate;
    *(float4*)(out + (size_t)idx * 4) = r;
}

extern "C" void kernel_launch(void* const* d_in, const int* in_sizes, int n_in,
                              void* d_out, int out_size, void* d_ws, size_t ws_size,
                              hipStream_t stream) {
    const float* t        = (const float*)d_in[0];
    const float* reduce_w = (const float*)d_in[1];
    const float* reduce_b = (const float*)d_in[2];
    const float* expand_w = (const float*)d_in[3];
    const float* expand_b = (const float*)d_in[4];
    float* out = (float*)d_out;

    float* pooled = (float*)d_ws;                 // 8*1024 fp32 = 32 KB
    float* s_buf  = pooled + Bsz * C16;           // 8*256  fp32 =  8 KB
    float* g_buf  = s_buf + Bsz * SQsz;           // 8*1024 fp32 = 32 KB

    pool_kernel  <<<Bsz * Csz * 16, 256, 0, stream>>>(t, pooled);
    reduce_kernel<<<Bsz,            256, 0, stream>>>(pooled, reduce_w, reduce_b, s_buf);
    expand_kernel<<<Bsz,            256, 0, stream>>>(s_buf, expand_w, expand_b, g_buf);
    scale_kernel <<<32768,          256, 0, stream>>>(t, g_buf, out);
}

// Round 3
// 259.157 us; speedup vs baseline: 1.2756x; 1.2756x over previous
//
#include <hip/hip_runtime.h>
#include <math.h>

// SE4 squeeze-excite, B=8, C=64, H=W=256, 4x4 patch grid (64x64 patches), SQ=256.
// ALL I/O float32. fp32 compute.
//
// R3 changes vs R2: reduce/expand restructured from 8 blocks (latency-bound,
// ~40us each: 1MB weights over 8 CUs) to wave-per-output-column with 8-way
// batch reuse in registers (256 / 1024 blocks, weights read exactly once).

#define Bsz 8
#define Csz 64
#define Hsz 256
#define Wsz 256
#define SQsz 256
#define C16 1024   // 16*C

// ---------------- kernel 1: patch pooling ----------------
// grid = B*C*16 = 8192 blocks of 256 threads. p = bid & 15 (= i*4+j), bc = bid>>4.
// Patch: 64 rows x 64 cols fp32 = 1024 float4 groups; each thread sums 4 groups.
__global__ __launch_bounds__(256) void pool_kernel(const float* __restrict__ t,
                                                   float* __restrict__ pooled) {
    int bid = blockIdx.x;
    int p   = bid & 15;
    int bc  = bid >> 4;          // b*C + c
    int i   = p >> 2, j = p & 3;
    const float* base = t + (((size_t)bc * Hsz + (size_t)i * 64) * Wsz + (size_t)j * 64);
    int tid = threadIdx.x;
    float sum = 0.f;
#pragma unroll
    for (int k = 0; k < 4; ++k) {
        int g    = tid + k * 256;          // 0..1023
        int row  = g >> 4;
        int col4 = g & 15;
        float4 v = *(const float4*)(base + (size_t)row * Wsz + col4 * 4);
        sum += v.x + v.y + v.z + v.w;
    }
#pragma unroll
    for (int off = 32; off > 0; off >>= 1) sum += __shfl_down(sum, off, 64);
    __shared__ float wsum[4];
    if ((tid & 63) == 0) wsum[tid >> 6] = sum;
    __syncthreads();
    if (tid == 0) {
        float s = wsum[0] + wsum[1] + wsum[2] + wsum[3];
        int b = bc >> 6;          // /C
        int c = bc & 63;
        pooled[b * C16 + p * Csz + c] = s * (1.0f / 4096.0f);
    }
}

// ---------------- kernel 2: s = mish(pooled @ reduce_w^T + reduce_b) ----------------
// grid = 256 blocks (one per sq output o), 64 threads (one wave).
// Lane l accumulates k = l + 64*m over K=1024 for ALL 8 batches (weight row
// read once, coalesced; pooled 32KB is L2-hot). Butterfly reduce, lanes 0-7 write.
__global__ __launch_bounds__(64) void reduce_kernel(const float* __restrict__ pooled,
                                                    const float* __restrict__ reduce_w,
                                                    const float* __restrict__ reduce_b,
                                                    float* __restrict__ s_out) {
    int o = blockIdx.x;
    int l = threadIdx.x;
    const float* wrow = reduce_w + (size_t)o * C16;
    float acc[Bsz] = {0.f, 0.f, 0.f, 0.f, 0.f, 0.f, 0.f, 0.f};
#pragma unroll
    for (int m = 0; m < 16; ++m) {
        int k = l + 64 * m;
        float wv = wrow[k];
#pragma unroll
        for (int b = 0; b < Bsz; ++b)
            acc[b] = fmaf(wv, pooled[b * C16 + k], acc[b]);
    }
#pragma unroll
    for (int off = 32; off > 0; off >>= 1) {
#pragma unroll
        for (int b = 0; b < Bsz; ++b)
            acc[b] += __shfl_xor(acc[b], off, 64);
    }
    if (l < Bsz) {
        float x = acc[l] + reduce_b[o];
        float sp = (x > 15.f) ? x : log1pf(expf(x));
        s_out[l * SQsz + o] = x * tanhf(sp);
    }
}

// ---------------- kernel 3: g = sigmoid(s @ expand_w^T + expand_b) ----------------
// grid = 1024 blocks (one per output o), 64 threads. K=256: lane l takes
// k = l + 64*m, m=0..3, for all 8 batches. s (8KB) is L2-hot.
__global__ __launch_bounds__(64) void expand_kernel(const float* __restrict__ s_in,
                                                    const float* __restrict__ expand_w,
                                                    const float* __restrict__ expand_b,
                                                    float* __restrict__ g_out) {
    int o = blockIdx.x;
    int l = threadIdx.x;
    const float* wrow = expand_w + (size_t)o * SQsz;
    float acc[Bsz] = {0.f, 0.f, 0.f, 0.f, 0.f, 0.f, 0.f, 0.f};
#pragma unroll
    for (int m = 0; m < 4; ++m) {
        int k = l + 64 * m;
        float wv = wrow[k];
#pragma unroll
        for (int b = 0; b < Bsz; ++b)
            acc[b] = fmaf(wv, s_in[b * SQsz + k], acc[b]);
    }
#pragma unroll
    for (int off = 32; off > 0; off >>= 1) {
#pragma unroll
        for (int b = 0; b < Bsz; ++b)
            acc[b] += __shfl_xor(acc[b], off, 64);
    }
    if (l < Bsz) {
        float x = acc[l] + expand_b[o];
        g_out[l * C16 + o] = 1.0f / (1.0f + expf(-x));
    }
}

// ---------------- kernel 4: out = t * gate ----------------
// One thread per float4 (4 | 64, never crosses a patch-column boundary).
// 33,554,432/4 = 8,388,608 threads -> 32768 blocks x 256.
__global__ __launch_bounds__(256) void scale_kernel(const float* __restrict__ t,
                                                    const float* __restrict__ g,
                                                    float* __restrict__ out) {
    unsigned int idx = blockIdx.x * 256u + threadIdx.x;   // float4 group index
    int w4 = idx & 63;                // w/4
    int h  = (idx >> 6) & 255;
    int c  = (idx >> 14) & 63;
    int b  = idx >> 20;
    int p  = ((h >> 6) << 2) | (w4 >> 4);    // i*4 + j
    float gate = g[(b << 10) + (p << 6) + c];
    float4 v = *(const float4*)(t + (size_t)idx * 4);
    float4 r;
    r.x = v.x * gate;
    r.y = v.y * gate;
    r.z = v.z * gate;
    r.w = v.w * gate;
    *(float4*)(out + (size_t)idx * 4) = r;
}

extern "C" void kernel_launch(void* const* d_in, const int* in_sizes, int n_in,
                              void* d_out, int out_size, void* d_ws, size_t ws_size,
                              hipStream_t stream) {
    const float* t        = (const float*)d_in[0];
    const float* reduce_w = (const float*)d_in[1];
    const float* reduce_b = (const float*)d_in[2];
    const float* expand_w = (const float*)d_in[3];
    const float* expand_b = (const float*)d_in[4];
    float* out = (float*)d_out;

    float* pooled = (float*)d_ws;                 // 8*1024 fp32 = 32 KB
    float* s_buf  = pooled + Bsz * C16;           // 8*256  fp32 =  8 KB
    float* g_buf  = s_buf + Bsz * SQsz;           // 8*1024 fp32 = 32 KB

    pool_kernel  <<<Bsz * Csz * 16, 256, 0, stream>>>(t, pooled);
    reduce_kernel<<<SQsz,            64, 0, stream>>>(pooled, reduce_w, reduce_b, s_buf);
    expand_kernel<<<C16,             64, 0, stream>>>(s_buf, expand_w, expand_b, g_buf);
    scale_kernel <<<32768,          256, 0, stream>>>(t, g_buf, out);
}